// Round 8
// baseline (759.058 us; speedup 1.0000x reference)
//
#include <hip/hip_runtime.h>
#include <cstdint>
#include <cstddef>

typedef unsigned short u16;
typedef unsigned int   u32;
typedef __attribute__((ext_vector_type(8))) short short8;
typedef __attribute__((ext_vector_type(4))) float floatx4;

__device__ __forceinline__ float asf(u32 u){ union{u32 u; float f;} v; v.u=u; return v.f; }
__device__ __forceinline__ u32 asu(float f){ union{float f; u32 u;} v; v.f=f; return v.u; }
__device__ __forceinline__ float bf2f(u16 u){ return asf(((u32)u)<<16); }
__device__ __forceinline__ u16 f2bf(float f){ u32 u = asu(f); u32 r = u + 0x7FFFu + ((u>>16)&1u); return (u16)(r>>16); }
__device__ __forceinline__ u32 pack2(float a, float b){ return (u32)f2bf(a) | (((u32)f2bf(b))<<16); }
__device__ __forceinline__ void bf8f(uint4 d, float* o){
  o[0]=asf(d.x<<16); o[1]=asf(d.x&0xFFFF0000u);
  o[2]=asf(d.y<<16); o[3]=asf(d.y&0xFFFF0000u);
  o[4]=asf(d.z<<16); o[5]=asf(d.z&0xFFFF0000u);
  o[6]=asf(d.w<<16); o[7]=asf(d.w&0xFFFF0000u);
}

// ---------------------------------------------------------------------------
// fp32 -> bf16 conversion (weights), 8 elems/thread
// ---------------------------------------------------------------------------
__global__ __launch_bounds__(256) void cvt_f32_bf16(
    const float* __restrict__ in, u16* __restrict__ out, int n)
{
  const int i = (blockIdx.x*256 + threadIdx.x)*8;
  if (i >= n) return;
  const float4 a = *(const float4*)(in + i);
  const float4 b = *(const float4*)(in + i + 4);
  uint4 st;
  st.x = pack2(a.x, a.y); st.y = pack2(a.z, a.w);
  st.z = pack2(b.x, b.y); st.w = pack2(b.z, b.w);
  *(uint4*)(out + i) = st;
}

// ---------------------------------------------------------------------------
// MFMA GEMM: C[M,N] = A[M,K] @ B[N,K]^T, bf16 in, fp32 accum.
// 128x128 tile, BK=32, 4 waves, each wave 64x64 (4x4 of 16x16x32 MFMA).
// OutT = u16 (bf16 store) or float (fp32 store).
// Validated equivalent to naive reference (R7 comparator).
// ---------------------------------------------------------------------------
enum { EPI_NONE=0, EPI_BIAS_GELU=1, EPI_BIAS_RES=2 };

template<int EPI, typename OutT>
__global__ __launch_bounds__(256) void gemm_bt(
    const u16* __restrict__ A, const u16* __restrict__ B,
    const float* __restrict__ bias, const float* __restrict__ res,
    OutT* __restrict__ C, int M, int N, int K)
{
  __shared__ u16 As[128*32];
  __shared__ u16 Bs[128*32];
  const int tid  = threadIdx.x;
  const int wave = tid >> 6;
  const int lane = tid & 63;
  const int bm = blockIdx.y, bn = blockIdx.x;

  const int srow = wave*16 + (lane>>2);   // staging row within 64-row slab
  const int scol = (lane&3)*8;            // staging col (8 bf16 = 16B)
  const u16* Ag = A + (size_t)bm*128*K;
  const u16* Bg = B + (size_t)bn*128*K;

  const int wm = (wave>>1)*64;
  const int wn = (wave&1)*64;
  const int fr = lane & 15;               // m (or n) within 16-tile
  const int fk = (lane>>4)*8;             // k offset (quad*8)

  floatx4 acc[4][4] = {};

  for (int k0 = 0; k0 < K; k0 += 32) {
    __syncthreads();
    #pragma unroll
    for (int t = 0; t < 2; ++t) {
      __builtin_amdgcn_global_load_lds(
          (__attribute__((address_space(1))) void*)(Ag + (t*64 + srow)*K + k0 + scol),
          (__attribute__((address_space(3))) void*)(As + (t*64 + wave*16)*32),
          16, 0, 0);
      __builtin_amdgcn_global_load_lds(
          (__attribute__((address_space(1))) void*)(Bg + (t*64 + srow)*K + k0 + scol),
          (__attribute__((address_space(3))) void*)(Bs + (t*64 + wave*16)*32),
          16, 0, 0);
    }
    __syncthreads();

    short8 af[4], bfr[4];
    #pragma unroll
    for (int i=0;i<4;i++) af[i]  = *(const short8*)(As + (wm + i*16 + fr)*32 + fk);
    #pragma unroll
    for (int j=0;j<4;j++) bfr[j] = *(const short8*)(Bs + (wn + j*16 + fr)*32 + fk);
    #pragma unroll
    for (int i=0;i<4;i++)
      #pragma unroll
      for (int j=0;j<4;j++)
        acc[i][j] = __builtin_amdgcn_mfma_f32_16x16x32_bf16(af[i], bfr[j], acc[i][j], 0, 0, 0);
  }

  // epilogue: C/D layout col=lane&15, row=(lane>>4)*4+reg
  const int col0 = bn*128 + wn + fr;
  float bv[4] = {0.f,0.f,0.f,0.f};
  if constexpr (EPI != EPI_NONE) {
    #pragma unroll
    for (int j=0;j<4;j++) bv[j] = bias[col0 + j*16];
  }
  const int rq = (lane>>4)*4;
  #pragma unroll
  for (int i=0;i<4;i++){
    #pragma unroll
    for (int rr=0;rr<4;rr++){
      const int m = bm*128 + wm + i*16 + rq + rr;
      const size_t rowoff = (size_t)m*N;
      #pragma unroll
      for (int j=0;j<4;j++){
        float vv = acc[i][j][rr];
        const int n = col0 + j*16;
        if constexpr (EPI == EPI_BIAS_GELU){
          vv += bv[j];
          vv = 0.5f*vv*(1.f + erff(vv*0.70710678118654752f));
        } else if constexpr (EPI == EPI_BIAS_RES){
          vv += bv[j] + res[rowoff + n];
        }
        if constexpr (sizeof(OutT) == 2) C[rowoff + n] = f2bf(vv);
        else                             C[rowoff + n] = vv;
      }
    }
  }
}

// ---------------------------------------------------------------------------
// LayerNorm over 512 (fp32 in, bf16 out), wave-per-row, 4 rows/block
// ---------------------------------------------------------------------------
__global__ __launch_bounds__(256) void ln512_kernel(
    const float* __restrict__ x, const float* __restrict__ w, const float* __restrict__ b,
    u16* __restrict__ out)
{
  const int row  = blockIdx.x*4 + (threadIdx.x>>6);
  const int lane = threadIdx.x & 63;
  const size_t base = (size_t)row*512 + lane*8;
  float v[8];
  { const float4 a = *(const float4*)(x + base);
    const float4 c = *(const float4*)(x + base + 4);
    v[0]=a.x; v[1]=a.y; v[2]=a.z; v[3]=a.w; v[4]=c.x; v[5]=c.y; v[6]=c.z; v[7]=c.w; }
  float s=0.f, sq=0.f;
  #pragma unroll
  for (int i=0;i<8;i++){ s += v[i]; sq += v[i]*v[i]; }
  for (int off=32; off>0; off>>=1){ s += __shfl_xor(s, off, 64); sq += __shfl_xor(sq, off, 64); }
  const float mu = s*(1.f/512.f);
  const float rs = rsqrtf(sq*(1.f/512.f) - mu*mu + 1e-5f);
  float o[8];
  #pragma unroll
  for (int i=0;i<8;i++)
    o[i] = (v[i]-mu)*rs*w[lane*8+i] + b[lane*8+i];
  uint4 st; st.x=pack2(o[0],o[1]); st.y=pack2(o[2],o[3]); st.z=pack2(o[4],o[5]); st.w=pack2(o[6],o[7]);
  *(uint4*)(out + base) = st;
}

// h = LN(ao)*w2+b2 + x (fp32 out) ; z = LN(h)*w3+b3 (bf16 out)
__global__ __launch_bounds__(256) void lnres_kernel(
    const u16* __restrict__ ao, const float* __restrict__ x,
    const float* __restrict__ w2, const float* __restrict__ b2,
    const float* __restrict__ w3, const float* __restrict__ b3,
    float* __restrict__ h, u16* __restrict__ z)
{
  const int row  = blockIdx.x*4 + (threadIdx.x>>6);
  const int lane = threadIdx.x & 63;
  const size_t base = (size_t)row*512 + lane*8;
  float a[8], xr[8];
  bf8f(*(const uint4*)(ao + base), a);
  { const float4 p = *(const float4*)(x + base);
    const float4 q = *(const float4*)(x + base + 4);
    xr[0]=p.x; xr[1]=p.y; xr[2]=p.z; xr[3]=p.w; xr[4]=q.x; xr[5]=q.y; xr[6]=q.z; xr[7]=q.w; }
  float s=0.f, sq=0.f;
  #pragma unroll
  for (int i=0;i<8;i++){ s += a[i]; sq += a[i]*a[i]; }
  for (int off=32; off>0; off>>=1){ s += __shfl_xor(s, off, 64); sq += __shfl_xor(sq, off, 64); }
  float mu = s*(1.f/512.f);
  float rs = rsqrtf(sq*(1.f/512.f) - mu*mu + 1e-5f);
  float hv[8];
  #pragma unroll
  for (int i=0;i<8;i++)
    hv[i] = (a[i]-mu)*rs*w2[lane*8+i] + b2[lane*8+i] + xr[i];
  { float4 p; p.x=hv[0]; p.y=hv[1]; p.z=hv[2]; p.w=hv[3];
    float4 q; q.x=hv[4]; q.y=hv[5]; q.z=hv[6]; q.w=hv[7];
    *(float4*)(h + base) = p; *(float4*)(h + base + 4) = q; }
  s=0.f; sq=0.f;
  #pragma unroll
  for (int i=0;i<8;i++){ s += hv[i]; sq += hv[i]*hv[i]; }
  for (int off=32; off>0; off>>=1){ s += __shfl_xor(s, off, 64); sq += __shfl_xor(sq, off, 64); }
  mu = s*(1.f/512.f);
  rs = rsqrtf(sq*(1.f/512.f) - mu*mu + 1e-5f);
  float zv[8];
  #pragma unroll
  for (int i=0;i<8;i++)
    zv[i] = (hv[i]-mu)*rs*w3[lane*8+i] + b3[lane*8+i];
  uint4 st; st.x=pack2(zv[0],zv[1]); st.y=pack2(zv[2],zv[3]); st.z=pack2(zv[4],zv[5]); st.w=pack2(zv[6],zv[7]);
  *(uint4*)(z + base) = st;
}

// LayerNorm over 2048 (bf16, in place safe: full row in regs before store)
__global__ __launch_bounds__(256) void ln2048_kernel(
    const u16* x, const float* __restrict__ w, const float* __restrict__ b,
    u16* out)
{
  const int row  = blockIdx.x*4 + (threadIdx.x>>6);
  const int lane = threadIdx.x & 63;
  const u16* xp = x + (size_t)row*2048;
  float v[32];
  #pragma unroll
  for (int g=0; g<4; ++g) bf8f(*(const uint4*)(xp + g*512 + lane*8), v + g*8);
  float s=0.f, sq=0.f;
  #pragma unroll
  for (int i=0;i<32;i++){ s += v[i]; sq += v[i]*v[i]; }
  for (int off=32; off>0; off>>=1){ s += __shfl_xor(s, off, 64); sq += __shfl_xor(sq, off, 64); }
  const float mu = s*(1.f/2048.f);
  const float rs = rsqrtf(sq*(1.f/2048.f) - mu*mu + 1e-5f);
  u16* op = out + (size_t)row*2048;
  #pragma unroll
  for (int g=0; g<4; ++g){
    float o[8];
    #pragma unroll
    for (int i=0;i<8;i++){
      const int idx = g*512 + lane*8 + i;
      o[i] = (v[g*8+i]-mu)*rs*w[idx] + b[idx];
    }
    uint4 st; st.x=pack2(o[0],o[1]); st.y=pack2(o[2],o[3]); st.z=pack2(o[4],o[5]); st.w=pack2(o[6],o[7]);
    *(uint4*)(op + g*512 + lane*8) = st;
  }
}

// ---------------------------------------------------------------------------
// Differential attention (exact softmax; scores bounded so exp is safe).
// Block 256 = 32 query rows x 8 col-threads. Grid 2048 = (b,h) x 32.
// Validated vs naive reference (R7 comparator).
// ---------------------------------------------------------------------------
#define ATT_SCALE 0.17677669529663687f   // 32^-0.5

__global__ __launch_bounds__(256) void attn_kernel(
    const u16* __restrict__ Q, const u16* __restrict__ K, const u16* __restrict__ V,
    const float* __restrict__ lq1, const float* __restrict__ lk1,
    const float* __restrict__ lq2, const float* __restrict__ lk2,
    const float* __restrict__ subw, u16* __restrict__ out)
{
  __shared__ u16 Ks[2][64][40];
  __shared__ u16 Vs[64][64];
  __shared__ float P1[32][68];
  __shared__ float P2[32][68];

  const int tid = threadIdx.x;
  const int bid = blockIdx.x;
  const int rb  = bid & 31;
  const int bh  = bid >> 5;
  const int b   = bh >> 3;
  const int h   = bh & 7;
  const int r   = tid >> 3;
  const int c   = tid & 7;

  float t1 = 0.f, t2 = 0.f;
  for (int i=0;i<32;i++){ t1 += lq1[i]*lk1[i]; t2 += lq2[i]*lk2[i]; }
  const float lam = expf(t1) - expf(t2) + 0.2f;   // LAMBDA_INIT = 0.2

  const int qrow = b*1024 + rb*32 + r;
  const u16* q1p = Q + (size_t)qrow*512 + (2*h)*32;
  float qf1[32], qf2[32];
  #pragma unroll
  for (int i=0;i<4;i++){
    bf8f(*(const uint4*)(q1p + i*8),      qf1 + i*8);
    bf8f(*(const uint4*)(q1p + 32 + i*8), qf2 + i*8);
  }
  #pragma unroll
  for (int i=0;i<32;i++){ qf1[i]*=ATT_SCALE; qf2[i]*=ATT_SCALE; }

  float l1=0.f, l2=0.f;
  float O1[8] = {0.f,0.f,0.f,0.f,0.f,0.f,0.f,0.f};
  float O2[8] = {0.f,0.f,0.f,0.f,0.f,0.f,0.f,0.f};
  const int kvbase = b*1024;

  for (int t = 0; t < 16; ++t) {
    const int j0 = t*64;
    {
      const int jr = tid >> 2;
      const int d0 = (tid & 3)*8;
      const u16* kp = K + (size_t)(kvbase + j0 + jr)*512 + 2*h*32;
      *(uint4*)&Ks[0][jr][d0] = *(const uint4*)(kp + d0);
      *(uint4*)&Ks[1][jr][d0] = *(const uint4*)(kp + 32 + d0);
      const u16* vp = V + (size_t)(kvbase + j0 + jr)*512 + h*64;
      *(uint4*)&Vs[jr][d0]      = *(const uint4*)(vp + d0);
      *(uint4*)&Vs[jr][d0 + 32] = *(const uint4*)(vp + d0 + 32);
    }
    __syncthreads();

    #pragma unroll
    for (int jj=0; jj<8; ++jj){
      const int j = jj*8 + c;
      float a1 = 0.f, a2 = 0.f;
      #pragma unroll
      for (int i4=0;i4<4;i4++){
        float kf1[8], kf2[8];
        bf8f(*(const uint4*)&Ks[0][j][i4*8], kf1);
        bf8f(*(const uint4*)&Ks[1][j][i4*8], kf2);
        #pragma unroll
        for (int u=0;u<8;u++){
          a1 += qf1[i4*8+u]*kf1[u];
          a2 += qf2[i4*8+u]*kf2[u];
        }
      }
      const float p1 = __expf(a1);
      const float p2 = __expf(a2);
      P1[r][j] = p1; P2[r][j] = p2;
      l1 += p1; l2 += p2;
    }
    __syncthreads();

    #pragma unroll 4
    for (int j=0;j<64;j++){
      const float p1 = P1[r][j];
      const float p2 = P2[r][j];
      float vf[8];
      bf8f(*(const uint4*)&Vs[j][c*8], vf);
      #pragma unroll
      for (int i=0;i<8;i++){ O1[i] += p1*vf[i]; O2[i] += p2*vf[i]; }
    }
    __syncthreads();
  }

  for (int off=1; off<8; off<<=1){
    l1 += __shfl_xor(l1, off, 64);
    l2 += __shfl_xor(l2, off, 64);
  }

  const float c1 = 1.f/l1;
  const float c2 = lam/l2;
  float o[8]; float ss = 0.f;
  #pragma unroll
  for (int i=0;i<8;i++){ o[i] = O1[i]*c1 - O2[i]*c2; ss += o[i]*o[i]; }
  for (int off=1; off<8; off<<=1) ss += __shfl_xor(ss, off, 64);
  const float rs = rsqrtf(ss*(1.f/64.f) + 1e-5f) * 0.8f;
  uint4 st;
  st.x = pack2(o[0]*rs*subw[c*8+0], o[1]*rs*subw[c*8+1]);
  st.y = pack2(o[2]*rs*subw[c*8+2], o[3]*rs*subw[c*8+3]);
  st.z = pack2(o[4]*rs*subw[c*8+4], o[5]*rs*subw[c*8+5]);
  st.w = pack2(o[6]*rs*subw[c*8+6], o[7]*rs*subw[c*8+7]);
  *(uint4*)(out + (size_t)qrow*512 + h*64 + c*8) = st;
}

// ---------------------------------------------------------------------------
extern "C" void kernel_launch(void* const* d_in, const int* in_sizes, int n_in,
                              void* d_out, int out_size, void* d_ws, size_t ws_size,
                              hipStream_t stream)
{
  (void)in_sizes; (void)n_in; (void)out_size; (void)ws_size;
  const float* x    = (const float*)d_in[0];
  const float* Wq   = (const float*)d_in[1];
  const float* Wk   = (const float*)d_in[2];
  const float* Wv   = (const float*)d_in[3];
  const float* Wo   = (const float*)d_in[4];
  const float* lq1  = (const float*)d_in[5];
  const float* lk1  = (const float*)d_in[6];
  const float* lq2  = (const float*)d_in[7];
  const float* lk2  = (const float*)d_in[8];
  const float* subw = (const float*)d_in[9];
  const float* n1w  = (const float*)d_in[10];
  const float* n1b  = (const float*)d_in[11];
  const float* n2w  = (const float*)d_in[12];
  const float* n2b  = (const float*)d_in[13];
  const float* m1w  = (const float*)d_in[14];
  const float* m1b  = (const float*)d_in[15];
  const float* mW1  = (const float*)d_in[16];
  const float* mb1  = (const float*)d_in[17];
  const float* m2w  = (const float*)d_in[18];
  const float* m2b  = (const float*)d_in[19];
  const float* mW2  = (const float*)d_in[20];
  const float* mb2  = (const float*)d_in[21];
  float* out = (float*)d_out;   // OUTPUT IS FP32 (reference returns float32)

  // Workspace: 86 MB (ws_size >= 113 MB proven by R7 naive path running).
  char* ws = (char*)d_ws;
  const size_t MB = (size_t)1 << 20;
  u16*  xn  = (u16*)(ws + 0*MB);    // [0,8)
  u16*  q   = (u16*)(ws + 8*MB);    // [8,16)
  u16*  k   = (u16*)(ws + 16*MB);   // [16,24)
  u16*  v   = (u16*)(ws + 24*MB);   // [24,32)
  u16*  a   = (u16*)(ws + 0*MB);    // reuse xn (dead after v-gemm)
  u16*  ao  = (u16*)(ws + 8*MB);    // reuse q  (dead after attn)
  u16*  z1  = (u16*)(ws + 16*MB);   // reuse k
  float* h  = (float*)(ws + 32*MB); // [32,48) fp32
  u16*  t   = (u16*)(ws + 48*MB);   // [48,80), LN2048 in place
  u16* Wqb  = (u16*)(ws + 80*MB);
  u16* Wkb  = (u16*)(ws + 80*MB + 512*1024);
  u16* Wvb  = (u16*)(ws + 81*MB);
  u16* Wob  = (u16*)(ws + 81*MB + 512*1024);
  u16* W1b  = (u16*)(ws + 82*MB);   // 2MB
  u16* W2b  = (u16*)(ws + 84*MB);   // 2MB -> ends 86MB

  const int M = 8192;

  cvt_f32_bf16<<<128, 256, 0, stream>>>(Wq, Wqb, 512*512);
  cvt_f32_bf16<<<128, 256, 0, stream>>>(Wk, Wkb, 512*512);
  cvt_f32_bf16<<<128, 256, 0, stream>>>(Wv, Wvb, 512*512);
  cvt_f32_bf16<<<128, 256, 0, stream>>>(Wo, Wob, 512*512);
  cvt_f32_bf16<<<512, 256, 0, stream>>>(mW1, W1b, 2048*512);
  cvt_f32_bf16<<<512, 256, 0, stream>>>(mW2, W2b, 2048*512);

  ln512_kernel<<<2048, 256, 0, stream>>>(x, n1w, n1b, xn);

  gemm_bt<EPI_NONE,u16><<<dim3(4,64), 256, 0, stream>>>(xn, Wqb, nullptr, nullptr, q, M, 512, 512);
  gemm_bt<EPI_NONE,u16><<<dim3(4,64), 256, 0, stream>>>(xn, Wkb, nullptr, nullptr, k, M, 512, 512);
  gemm_bt<EPI_NONE,u16><<<dim3(4,64), 256, 0, stream>>>(xn, Wvb, nullptr, nullptr, v, M, 512, 512);

  attn_kernel<<<2048, 256, 0, stream>>>(q, k, v, lq1, lk1, lq2, lk2, subw, a);

  gemm_bt<EPI_NONE,u16><<<dim3(4,64), 256, 0, stream>>>(a, Wob, nullptr, nullptr, ao, M, 512, 512);

  lnres_kernel<<<2048, 256, 0, stream>>>(ao, x, n2w, n2b, m1w, m1b, h, z1);

  gemm_bt<EPI_BIAS_GELU,u16><<<dim3(16,64), 256, 0, stream>>>(z1, W1b, mb1, nullptr, t, M, 2048, 512);

  ln2048_kernel<<<2048, 256, 0, stream>>>(t, m2w, m2b, t);

  gemm_bt<EPI_BIAS_RES,float><<<dim3(4,64), 256, 0, stream>>>(t, W2b, mb2, h, out, M, 512, 2048);
}

// Round 9
// 387.558 us; speedup vs baseline: 1.9586x; 1.9586x over previous
//
#include <hip/hip_runtime.h>
#include <cstdint>
#include <cstddef>

typedef unsigned short u16;
typedef unsigned int   u32;
typedef __attribute__((ext_vector_type(8))) short short8;
typedef __attribute__((ext_vector_type(4))) float floatx4;

__device__ __forceinline__ float asf(u32 u){ union{u32 u; float f;} v; v.u=u; return v.f; }
__device__ __forceinline__ u32 asu(float f){ union{float f; u32 u;} v; v.f=f; return v.u; }
__device__ __forceinline__ float bf2f(u16 u){ return asf(((u32)u)<<16); }
__device__ __forceinline__ u16 f2bf(float f){ u32 u = asu(f); u32 r = u + 0x7FFFu + ((u>>16)&1u); return (u16)(r>>16); }
__device__ __forceinline__ u32 pack2(float a, float b){ return (u32)f2bf(a) | (((u32)f2bf(b))<<16); }
__device__ __forceinline__ void bf8f(uint4 d, float* o){
  o[0]=asf(d.x<<16); o[1]=asf(d.x&0xFFFF0000u);
  o[2]=asf(d.y<<16); o[3]=asf(d.y&0xFFFF0000u);
  o[4]=asf(d.z<<16); o[5]=asf(d.z&0xFFFF0000u);
  o[6]=asf(d.w<<16); o[7]=asf(d.w&0xFFFF0000u);
}

// ---------------------------------------------------------------------------
// fp32 -> bf16 conversion (weights), 8 elems/thread
// ---------------------------------------------------------------------------
__global__ __launch_bounds__(256) void cvt_f32_bf16(
    const float* __restrict__ in, u16* __restrict__ out, int n)
{
  const int i = (blockIdx.x*256 + threadIdx.x)*8;
  if (i >= n) return;
  const float4 a = *(const float4*)(in + i);
  const float4 b = *(const float4*)(in + i + 4);
  uint4 st;
  st.x = pack2(a.x, a.y); st.y = pack2(a.z, a.w);
  st.z = pack2(b.x, b.y); st.w = pack2(b.z, b.w);
  *(uint4*)(out + i) = st;
}

// ---------------------------------------------------------------------------
// MFMA GEMM: C[M,N] = A[M,K] @ B[N,K]^T, bf16 in, fp32 accum.
// 128x128 tile, BK=32, 4 waves, each wave 64x64 (4x4 of 16x16x32 MFMA).
// ---------------------------------------------------------------------------
enum { EPI_NONE=0, EPI_BIAS_GELU=1, EPI_BIAS_RES=2 };

template<int EPI, typename OutT>
__global__ __launch_bounds__(256) void gemm_bt(
    const u16* __restrict__ A, const u16* __restrict__ B,
    const float* __restrict__ bias, const float* __restrict__ res,
    OutT* __restrict__ C, int M, int N, int K)
{
  __shared__ u16 As[128*32];
  __shared__ u16 Bs[128*32];
  const int tid  = threadIdx.x;
  const int wave = tid >> 6;
  const int lane = tid & 63;
  const int bm = blockIdx.y, bn = blockIdx.x;

  const int srow = wave*16 + (lane>>2);
  const int scol = (lane&3)*8;
  const u16* Ag = A + (size_t)bm*128*K;
  const u16* Bg = B + (size_t)bn*128*K;

  const int wm = (wave>>1)*64;
  const int wn = (wave&1)*64;
  const int fr = lane & 15;
  const int fk = (lane>>4)*8;

  floatx4 acc[4][4] = {};

  for (int k0 = 0; k0 < K; k0 += 32) {
    __syncthreads();
    #pragma unroll
    for (int t = 0; t < 2; ++t) {
      __builtin_amdgcn_global_load_lds(
          (__attribute__((address_space(1))) void*)(Ag + (t*64 + srow)*K + k0 + scol),
          (__attribute__((address_space(3))) void*)(As + (t*64 + wave*16)*32),
          16, 0, 0);
      __builtin_amdgcn_global_load_lds(
          (__attribute__((address_space(1))) void*)(Bg + (t*64 + srow)*K + k0 + scol),
          (__attribute__((address_space(3))) void*)(Bs + (t*64 + wave*16)*32),
          16, 0, 0);
    }
    __syncthreads();

    short8 af[4], bfr[4];
    #pragma unroll
    for (int i=0;i<4;i++) af[i]  = *(const short8*)(As + (wm + i*16 + fr)*32 + fk);
    #pragma unroll
    for (int j=0;j<4;j++) bfr[j] = *(const short8*)(Bs + (wn + j*16 + fr)*32 + fk);
    #pragma unroll
    for (int i=0;i<4;i++)
      #pragma unroll
      for (int j=0;j<4;j++)
        acc[i][j] = __builtin_amdgcn_mfma_f32_16x16x32_bf16(af[i], bfr[j], acc[i][j], 0, 0, 0);
  }

  const int col0 = bn*128 + wn + fr;
  float bv[4] = {0.f,0.f,0.f,0.f};
  if constexpr (EPI != EPI_NONE) {
    #pragma unroll
    for (int j=0;j<4;j++) bv[j] = bias[col0 + j*16];
  }
  const int rq = (lane>>4)*4;
  #pragma unroll
  for (int i=0;i<4;i++){
    #pragma unroll
    for (int rr=0;rr<4;rr++){
      const int m = bm*128 + wm + i*16 + rq + rr;
      const size_t rowoff = (size_t)m*N;
      #pragma unroll
      for (int j=0;j<4;j++){
        float vv = acc[i][j][rr];
        const int n = col0 + j*16;
        if constexpr (EPI == EPI_BIAS_GELU){
          vv += bv[j];
          vv = 0.5f*vv*(1.f + erff(vv*0.70710678118654752f));
        } else if constexpr (EPI == EPI_BIAS_RES){
          vv += bv[j] + res[rowoff + n];
        }
        if constexpr (sizeof(OutT) == 2) C[rowoff + n] = f2bf(vv);
        else                             C[rowoff + n] = vv;
      }
    }
  }
}

// ---------------------------------------------------------------------------
// LayerNorm over 512 (fp32 in, bf16 out), wave-per-row, 4 rows/block
// ---------------------------------------------------------------------------
__global__ __launch_bounds__(256) void ln512_kernel(
    const float* __restrict__ x, const float* __restrict__ w, const float* __restrict__ b,
    u16* __restrict__ out)
{
  const int row  = blockIdx.x*4 + (threadIdx.x>>6);
  const int lane = threadIdx.x & 63;
  const size_t base = (size_t)row*512 + lane*8;
  float v[8];
  { const float4 a = *(const float4*)(x + base);
    const float4 c = *(const float4*)(x + base + 4);
    v[0]=a.x; v[1]=a.y; v[2]=a.z; v[3]=a.w; v[4]=c.x; v[5]=c.y; v[6]=c.z; v[7]=c.w; }
  float s=0.f, sq=0.f;
  #pragma unroll
  for (int i=0;i<8;i++){ s += v[i]; sq += v[i]*v[i]; }
  for (int off=32; off>0; off>>=1){ s += __shfl_xor(s, off, 64); sq += __shfl_xor(sq, off, 64); }
  const float mu = s*(1.f/512.f);
  const float rs = rsqrtf(sq*(1.f/512.f) - mu*mu + 1e-5f);
  float o[8];
  #pragma unroll
  for (int i=0;i<8;i++)
    o[i] = (v[i]-mu)*rs*w[lane*8+i] + b[lane*8+i];
  uint4 st; st.x=pack2(o[0],o[1]); st.y=pack2(o[2],o[3]); st.z=pack2(o[4],o[5]); st.w=pack2(o[6],o[7]);
  *(uint4*)(out + base) = st;
}

// h = LN(ao)*w2+b2 + x (fp32 out) ; z = LN(h)*w3+b3 (bf16 out)
__global__ __launch_bounds__(256) void lnres_kernel(
    const u16* __restrict__ ao, const float* __restrict__ x,
    const float* __restrict__ w2, const float* __restrict__ b2,
    const float* __restrict__ w3, const float* __restrict__ b3,
    float* __restrict__ h, u16* __restrict__ z)
{
  const int row  = blockIdx.x*4 + (threadIdx.x>>6);
  const int lane = threadIdx.x & 63;
  const size_t base = (size_t)row*512 + lane*8;
  float a[8], xr[8];
  bf8f(*(const uint4*)(ao + base), a);
  { const float4 p = *(const float4*)(x + base);
    const float4 q = *(const float4*)(x + base + 4);
    xr[0]=p.x; xr[1]=p.y; xr[2]=p.z; xr[3]=p.w; xr[4]=q.x; xr[5]=q.y; xr[6]=q.z; xr[7]=q.w; }
  float s=0.f, sq=0.f;
  #pragma unroll
  for (int i=0;i<8;i++){ s += a[i]; sq += a[i]*a[i]; }
  for (int off=32; off>0; off>>=1){ s += __shfl_xor(s, off, 64); sq += __shfl_xor(sq, off, 64); }
  float mu = s*(1.f/512.f);
  float rs = rsqrtf(sq*(1.f/512.f) - mu*mu + 1e-5f);
  float hv[8];
  #pragma unroll
  for (int i=0;i<8;i++)
    hv[i] = (a[i]-mu)*rs*w2[lane*8+i] + b2[lane*8+i] + xr[i];
  { float4 p; p.x=hv[0]; p.y=hv[1]; p.z=hv[2]; p.w=hv[3];
    float4 q; q.x=hv[4]; q.y=hv[5]; q.z=hv[6]; q.w=hv[7];
    *(float4*)(h + base) = p; *(float4*)(h + base + 4) = q; }
  s=0.f; sq=0.f;
  #pragma unroll
  for (int i=0;i<8;i++){ s += hv[i]; sq += hv[i]*hv[i]; }
  for (int off=32; off>0; off>>=1){ s += __shfl_xor(s, off, 64); sq += __shfl_xor(sq, off, 64); }
  mu = s*(1.f/512.f);
  rs = rsqrtf(sq*(1.f/512.f) - mu*mu + 1e-5f);
  float zv[8];
  #pragma unroll
  for (int i=0;i<8;i++)
    zv[i] = (hv[i]-mu)*rs*w3[lane*8+i] + b3[lane*8+i];
  uint4 st; st.x=pack2(zv[0],zv[1]); st.y=pack2(zv[2],zv[3]); st.z=pack2(zv[4],zv[5]); st.w=pack2(zv[6],zv[7]);
  *(uint4*)(z + base) = st;
}

// LayerNorm over 2048 (bf16, in place safe)
__global__ __launch_bounds__(256) void ln2048_kernel(
    const u16* x, const float* __restrict__ w, const float* __restrict__ b,
    u16* out)
{
  const int row  = blockIdx.x*4 + (threadIdx.x>>6);
  const int lane = threadIdx.x & 63;
  const u16* xp = x + (size_t)row*2048;
  float v[32];
  #pragma unroll
  for (int g=0; g<4; ++g) bf8f(*(const uint4*)(xp + g*512 + lane*8), v + g*8);
  float s=0.f, sq=0.f;
  #pragma unroll
  for (int i=0;i<32;i++){ s += v[i]; sq += v[i]*v[i]; }
  for (int off=32; off>0; off>>=1){ s += __shfl_xor(s, off, 64); sq += __shfl_xor(sq, off, 64); }
  const float mu = s*(1.f/2048.f);
  const float rs = rsqrtf(sq*(1.f/2048.f) - mu*mu + 1e-5f);
  u16* op = out + (size_t)row*2048;
  #pragma unroll
  for (int g=0; g<4; ++g){
    float o[8];
    #pragma unroll
    for (int i=0;i<8;i++){
      const int idx = g*512 + lane*8 + i;
      o[i] = (v[g*8+i]-mu)*rs*w[idx] + b[idx];
    }
    uint4 st; st.x=pack2(o[0],o[1]); st.y=pack2(o[2],o[3]); st.z=pack2(o[4],o[5]); st.w=pack2(o[6],o[7]);
    *(uint4*)(op + g*512 + lane*8) = st;
  }
}

// ---------------------------------------------------------------------------
// MFMA differential flash attention.
// Block = 256 thr (4 waves) = one (b,h) x 64 Q rows; wave = 16 Q rows.
// Grid = 64 bh x 16 q-tiles = 1024.
// Per 64-key tile: K staged via global_load_lds (m97 pattern); V staged
// transposed (Vt[dim][key], two 32-key halves, stride-32 rows); QK^T via
// mfma_16x16x32 (K=hd=32 exactly); P -> LDS (bf16) -> A-frag (m120 pattern);
// PV via mfma. Exact softmax (scores bounded; validated R7/R8).
// ---------------------------------------------------------------------------
#define ATT_SCALE 0.17677669529663687f   // 32^-0.5

__global__ __launch_bounds__(256) void attn_mfma(
    const u16* __restrict__ Q, const u16* __restrict__ K, const u16* __restrict__ V,
    const float* __restrict__ lq1, const float* __restrict__ lk1,
    const float* __restrict__ lq2, const float* __restrict__ lk2,
    const float* __restrict__ subw, u16* __restrict__ out)
{
  __shared__ __align__(16) u16 Ks1[64*32];        // K sub1 [key][32]
  __shared__ __align__(16) u16 Ks2[64*32];        // K sub2
  __shared__ __align__(16) u16 VtA[64*32];        // V^T [dim][key 0..31]
  __shared__ __align__(16) u16 VtB[64*32];        // V^T [dim][key 32..63]
  __shared__ __align__(16) u16 PsBuf[2][2][4][16*40];  // [sub][khalf][wave][row*40]

  const int tid  = threadIdx.x;
  const int wave = tid >> 6;
  const int lane = tid & 63;
  const int quad = lane >> 4;
  const int l15  = lane & 15;

  const int bid = blockIdx.x;
  const int bh  = bid >> 4;
  const int qt  = bid & 15;
  const int b   = bh >> 3;
  const int h   = bh & 7;

  float t1 = 0.f, t2 = 0.f;
  for (int i=0;i<32;i++){ t1 += lq1[i]*lk1[i]; t2 += lq2[i]*lk2[i]; }
  const float lam = __expf(t1) - __expf(t2) + 0.2f;   // LAMBDA_INIT = 0.2

  // Q A-fragments: m = l15 (q row), k = quad*8..+8
  const int qrowg = b*1024 + qt*64 + wave*16 + l15;
  const short8 aq1 = *(const short8*)(Q + (size_t)qrowg*512 + 2*h*32 + quad*8);
  const short8 aq2 = *(const short8*)(Q + (size_t)qrowg*512 + 2*h*32 + 32 + quad*8);

  floatx4 O1[4] = {}, O2[4] = {};
  float l1acc[4] = {0.f,0.f,0.f,0.f};
  float l2acc[4] = {0.f,0.f,0.f,0.f};
  const floatx4 zf4 = {0.f,0.f,0.f,0.f};

  const int kvbase = b*1024;
  u16* p1w[2] = { &PsBuf[0][0][wave][0], &PsBuf[0][1][wave][0] };
  u16* p2w[2] = { &PsBuf[1][0][wave][0], &PsBuf[1][1][wave][0] };

  for (int kb = 0; kb < 1024; kb += 64) {
    __syncthreads();   // previous tile's LDS reads done

    // --- stage K (global_load_lds, m97 pattern): wave w -> rows w*16..+16
    {
      const u16* Kb = K + (size_t)(kvbase + kb)*512 + 2*h*32;
      const int srow = wave*16 + (lane>>2);
      const int scol = (lane&3)*8;
      __builtin_amdgcn_global_load_lds(
          (__attribute__((address_space(1))) void*)(Kb + (size_t)srow*512 + scol),
          (__attribute__((address_space(3))) void*)(Ks1 + wave*16*32),
          16, 0, 0);
      __builtin_amdgcn_global_load_lds(
          (__attribute__((address_space(1))) void*)(Kb + (size_t)srow*512 + 32 + scol),
          (__attribute__((address_space(3))) void*)(Ks2 + wave*16*32),
          16, 0, 0);
    }
    // --- stage V transposed: wave = dim group, lane = key
    {
      const u16* vp = V + (size_t)(kvbase + kb + lane)*512 + h*64 + wave*16;
      union { uint4 u4[2]; u16 us[16]; } vv;
      vv.u4[0] = *(const uint4*)(vp);
      vv.u4[1] = *(const uint4*)(vp + 8);
      u16* vt = ((lane & 32) ? VtB : VtA) + (lane & 31);
      #pragma unroll
      for (int i=0;i<16;i++) vt[(wave*16 + i)*32] = vv.us[i];
    }
    __syncthreads();   // staging visible

    // --- QK^T -> exp -> Ps (bf16) + l partials
    float l1p[4] = {0.f,0.f,0.f,0.f};
    float l2p[4] = {0.f,0.f,0.f,0.f};
    #pragma unroll
    for (int kt=0; kt<4; ++kt){
      const short8 bk1 = *(const short8*)(Ks1 + (kt*16 + l15)*32 + quad*8);
      const short8 bk2 = *(const short8*)(Ks2 + (kt*16 + l15)*32 + quad*8);
      const floatx4 s1 = __builtin_amdgcn_mfma_f32_16x16x32_bf16(aq1, bk1, zf4, 0, 0, 0);
      const floatx4 s2 = __builtin_amdgcn_mfma_f32_16x16x32_bf16(aq2, bk2, zf4, 0, 0, 0);
      u16* d1 = p1w[kt>>1] + (kt&1)*16 + l15;
      u16* d2 = p2w[kt>>1] + (kt&1)*16 + l15;
      #pragma unroll
      for (int rr=0; rr<4; ++rr){
        const float p1 = __expf(s1[rr]*ATT_SCALE);
        const float p2 = __expf(s2[rr]*ATT_SCALE);
        d1[(quad*4+rr)*40] = f2bf(p1);
        d2[(quad*4+rr)*40] = f2bf(p2);
        l1p[rr] += p1;
        l2p[rr] += p2;
      }
    }
    // row sums over the 16 key-lanes (stays within quad; row = quad*4+rr)
    #pragma unroll
    for (int rr=0; rr<4; ++rr){
      float v1 = l1p[rr], v2 = l2p[rr];
      v1 += __shfl_xor(v1, 1, 64); v2 += __shfl_xor(v2, 1, 64);
      v1 += __shfl_xor(v1, 2, 64); v2 += __shfl_xor(v2, 2, 64);
      v1 += __shfl_xor(v1, 4, 64); v2 += __shfl_xor(v2, 4, 64);
      v1 += __shfl_xor(v1, 8, 64); v2 += __shfl_xor(v2, 8, 64);
      l1acc[rr] += v1; l2acc[rr] += v2;
    }
    __syncthreads();   // Ps visible (same-wave RAW via LDS + Vt reuse ordering)

    // --- PV: A = P (m120 A-frag), B = Vt
    short8 ap1[2], ap2[2];
    ap1[0] = *(const short8*)(p1w[0] + l15*40 + quad*8);
    ap1[1] = *(const short8*)(p1w[1] + l15*40 + quad*8);
    ap2[0] = *(const short8*)(p2w[0] + l15*40 + quad*8);
    ap2[1] = *(const short8*)(p2w[1] + l15*40 + quad*8);
    #pragma unroll
    for (int nt=0; nt<4; ++nt){
      const short8 bv0 = *(const short8*)(VtA + (nt*16 + l15)*32 + quad*8);
      const short8 bv1 = *(const short8*)(VtB + (nt*16 + l15)*32 + quad*8);
      O1[nt] = __builtin_amdgcn_mfma_f32_16x16x32_bf16(ap1[0], bv0, O1[nt], 0, 0, 0);
      O1[nt] = __builtin_amdgcn_mfma_f32_16x16x32_bf16(ap1[1], bv1, O1[nt], 0, 0, 0);
      O2[nt] = __builtin_amdgcn_mfma_f32_16x16x32_bf16(ap2[0], bv0, O2[nt], 0, 0, 0);
      O2[nt] = __builtin_amdgcn_mfma_f32_16x16x32_bf16(ap2[1], bv1, O2[nt], 0, 0, 0);
    }
  }

  // --- epilogue: combine, rmsnorm over 64 dims, *0.8, store bf16
  float sw[4];
  #pragma unroll
  for (int nt=0; nt<4; ++nt) sw[nt] = subw[nt*16 + l15];

  #pragma unroll
  for (int rr=0; rr<4; ++rr){
    const int row = quad*4 + rr;
    const float il1 = 1.f / l1acc[rr];
    const float cl2 = lam / l2acc[rr];
    float o[4]; float ss = 0.f;
    #pragma unroll
    for (int nt=0; nt<4; ++nt){
      o[nt] = O1[nt][rr]*il1 - O2[nt][rr]*cl2;
      ss += o[nt]*o[nt];
    }
    ss += __shfl_xor(ss, 1, 64);
    ss += __shfl_xor(ss, 2, 64);
    ss += __shfl_xor(ss, 4, 64);
    ss += __shfl_xor(ss, 8, 64);
    const float rs = rsqrtf(ss*(1.f/64.f) + 1e-5f) * 0.8f;
    const int orow = b*1024 + qt*64 + wave*16 + row;
    u16* op = out + (size_t)orow*512 + h*64 + l15;
    #pragma unroll
    for (int nt=0; nt<4; ++nt)
      op[nt*16] = f2bf(o[nt]*rs*sw[nt]);
  }
}

// ---------------------------------------------------------------------------
extern "C" void kernel_launch(void* const* d_in, const int* in_sizes, int n_in,
                              void* d_out, int out_size, void* d_ws, size_t ws_size,
                              hipStream_t stream)
{
  (void)in_sizes; (void)n_in; (void)out_size; (void)ws_size;
  const float* x    = (const float*)d_in[0];
  const float* Wq   = (const float*)d_in[1];
  const float* Wk   = (const float*)d_in[2];
  const float* Wv   = (const float*)d_in[3];
  const float* Wo   = (const float*)d_in[4];
  const float* lq1  = (const float*)d_in[5];
  const float* lk1  = (const float*)d_in[6];
  const float* lq2  = (const float*)d_in[7];
  const float* lk2  = (const float*)d_in[8];
  const float* subw = (const float*)d_in[9];
  const float* n1w  = (const float*)d_in[10];
  const float* n1b  = (const float*)d_in[11];
  const float* n2w  = (const float*)d_in[12];
  const float* n2b  = (const float*)d_in[13];
  const float* m1w  = (const float*)d_in[14];
  const float* m1b  = (const float*)d_in[15];
  const float* mW1  = (const float*)d_in[16];
  const float* mb1  = (const float*)d_in[17];
  const float* m2w  = (const float*)d_in[18];
  const float* m2b  = (const float*)d_in[19];
  const float* mW2  = (const float*)d_in[20];
  const float* mb2  = (const float*)d_in[21];
  float* out = (float*)d_out;   // fp32 output

  char* ws = (char*)d_ws;
  const size_t MB = (size_t)1 << 20;
  u16*  xn  = (u16*)(ws + 0*MB);
  u16*  q   = (u16*)(ws + 8*MB);
  u16*  k   = (u16*)(ws + 16*MB);
  u16*  v   = (u16*)(ws + 24*MB);
  u16*  a   = (u16*)(ws + 0*MB);    // reuse xn
  u16*  ao  = (u16*)(ws + 8*MB);    // reuse q
  u16*  z1  = (u16*)(ws + 16*MB);   // reuse k
  float* h  = (float*)(ws + 32*MB);
  u16*  t   = (u16*)(ws + 48*MB);   // [48,80), LN2048 in place
  u16* Wqb  = (u16*)(ws + 80*MB);
  u16* Wkb  = (u16*)(ws + 80*MB + 512*1024);
  u16* Wvb  = (u16*)(ws + 81*MB);
  u16* Wob  = (u16*)(ws + 81*MB + 512*1024);
  u16* W1b  = (u16*)(ws + 82*MB);
  u16* W2b  = (u16*)(ws + 84*MB);

  const int M = 8192;

  cvt_f32_bf16<<<128, 256, 0, stream>>>(Wq, Wqb, 512*512);
  cvt_f32_bf16<<<128, 256, 0, stream>>>(Wk, Wkb, 512*512);
  cvt_f32_bf16<<<128, 256, 0, stream>>>(Wv, Wvb, 512*512);
  cvt_f32_bf16<<<128, 256, 0, stream>>>(Wo, Wob, 512*512);
  cvt_f32_bf16<<<512, 256, 0, stream>>>(mW1, W1b, 2048*512);
  cvt_f32_bf16<<<512, 256, 0, stream>>>(mW2, W2b, 2048*512);

  ln512_kernel<<<2048, 256, 0, stream>>>(x, n1w, n1b, xn);

  gemm_bt<EPI_NONE,u16><<<dim3(4,64), 256, 0, stream>>>(xn, Wqb, nullptr, nullptr, q, M, 512, 512);
  gemm_bt<EPI_NONE,u16><<<dim3(4,64), 256, 0, stream>>>(xn, Wkb, nullptr, nullptr, k, M, 512, 512);
  gemm_bt<EPI_NONE,u16><<<dim3(4,64), 256, 0, stream>>>(xn, Wvb, nullptr, nullptr, v, M, 512, 512);

  attn_mfma<<<1024, 256, 0, stream>>>(q, k, v, lq1, lk1, lq2, lk2, subw, a);

  gemm_bt<EPI_NONE,u16><<<dim3(4,64), 256, 0, stream>>>(a, Wob, nullptr, nullptr, ao, M, 512, 512);

  lnres_kernel<<<2048, 256, 0, stream>>>(ao, x, n2w, n2b, m1w, m1b, h, z1);

  gemm_bt<EPI_BIAS_GELU,u16><<<dim3(16,64), 256, 0, stream>>>(z1, W1b, mb1, nullptr, t, M, 2048, 512);

  ln2048_kernel<<<2048, 256, 0, stream>>>(t, m2w, m2b, t);

  gemm_bt<EPI_BIAS_RES,float><<<dim3(4,64), 256, 0, stream>>>(t, W2b, mb2, h, out, M, 512, 2048);
}